// Round 6
// baseline (424.185 us; speedup 1.0000x reference)
//
#include <hip/hip_runtime.h>

// ---------------------------------------------------------------------------
// Fused MHA block on MI355X (gfx950). fp16 MFMA 16x16x32, fp32 accum.
// Round-6:
//  * GEMM engine reverted to 16x16x32 (round-4 validated: 0 LDS conflicts).
//    The 32x32x16 fragment mapping caused 1.26e7 bank conflicts -> +7% dur.
//  * wo-GEMM: split-K=2 -> grid (16,32,2)=1024 blocks (4/CU, was 2/CU at
//    300 TF). Partials into DEAD ws regions (xh..vth, 67 MB, free after
//    flash); fp32 add-reduce kernel writes d_out.
//  * x + 4 weights converted in ONE dispatch.
// ---------------------------------------------------------------------------

typedef _Float16 half8 __attribute__((ext_vector_type(8)));
typedef float floatx4 __attribute__((ext_vector_type(4)));

__device__ __forceinline__ void async16(const void* g, void* l) {
  __builtin_amdgcn_global_load_lds((__attribute__((address_space(1))) void*)(g),
                                   (__attribute__((address_space(3))) void*)(l),
                                   16, 0, 0);
}

// ---- fp32 -> fp16 convert: x (2^21 quads) then 4 weights (2^20 each) -------
__global__ void cvt_all(const float* __restrict__ x, const float* __restrict__ w0,
                        const float* __restrict__ w1, const float* __restrict__ w2,
                        const float* __restrict__ w3, _Float16* __restrict__ xh,
                        _Float16* __restrict__ wh, float scale0) {
  int i = blockIdx.x * blockDim.x + threadIdx.x;
  const int XQ = 1 << 21;
  float sc = 1.0f;
  const float* src;
  _Float16* dst;
  int j;
  if (i < XQ) { src = x; dst = xh; j = i; }
  else {
    int t = i - XQ;
    int m = t >> 20;
    src = (m == 0) ? w0 : (m == 1) ? w1 : (m == 2) ? w2 : w3;
    if (m == 0) sc = scale0;
    dst = wh; j = t;                 // weights contiguous; src indexed by t&mask
  }
  int js = (i < XQ) ? j : (j & ((1 << 20) - 1));
  float4 v = reinterpret_cast<const float4*>(src)[js];
  union { _Float16 h[4]; short4 s; } u;
  u.h[0] = (_Float16)(v.x * sc); u.h[1] = (_Float16)(v.y * sc);
  u.h[2] = (_Float16)(v.z * sc); u.h[3] = (_Float16)(v.w * sc);
  reinterpret_cast<short4*>(dst)[j] = u.s;
}

// ---- NT GEMM (16x16x32): C[m][n] = sum_k A[m][k]*Bw[n][k], 128x128 tile ----
// OUT_MODE 0: fused QKV epilogue. OUT_MODE 2: split-K fp32 partial store.
template <int OUT_MODE>
__global__ __launch_bounds__(256)
void gemm_nt(const _Float16* __restrict__ A, const _Float16* __restrict__ Bw,
             void* __restrict__ Cv, void* __restrict__ Cv2, int kLen) {
  __shared__ _Float16 As[128 * 64];
  __shared__ _Float16 Bs[128 * 64];
  const int tid = threadIdx.x;
  const int wave = tid >> 6, lane = tid & 63;
  const int wm = wave >> 1, wn = wave & 1;
  const int l15 = lane & 15, l4 = lane >> 4;
  const int bm = blockIdx.y, bn = blockIdx.x;
  const int kStart = (OUT_MODE == 2) ? blockIdx.z * kLen : 0;

  floatx4 acc[4][4] = {};

  for (int k0 = kStart; k0 < kStart + kLen; k0 += 64) {
    __syncthreads();
#pragma unroll
    for (int i = 0; i < 4; ++i) {
      int c = i * 256 + tid;
      int row = c >> 3, cc = c & 7;
      int g = cc ^ (row & 7);                       // xor-swizzle global chunk
      async16(A + (size_t)(bm * 128 + row) * 2048 + k0 + g * 8, &As[c * 8]);
      async16(Bw + (size_t)(bn * 128 + row) * 2048 + k0 + g * 8, &Bs[c * 8]);
    }
    __syncthreads();
#pragma unroll
    for (int ks = 0; ks < 2; ++ks) {
      half8 af[4], bf[4];
      int ch = (ks * 4 + l4) ^ (l15 & 7);           // matching read swizzle
#pragma unroll
      for (int t = 0; t < 4; ++t) {
        af[t] = *reinterpret_cast<const half8*>(&As[(wm * 64 + t * 16 + l15) * 64 + ch * 8]);
        bf[t] = *reinterpret_cast<const half8*>(&Bs[(wn * 64 + t * 16 + l15) * 64 + ch * 8]);
      }
#pragma unroll
      for (int mt = 0; mt < 4; ++mt)
#pragma unroll
        for (int nt = 0; nt < 4; ++nt)
          acc[mt][nt] = __builtin_amdgcn_mfma_f32_16x16x32_f16(af[mt], bf[nt], acc[mt][nt], 0, 0, 0);
    }
  }

  const int rbase = bm * 128 + wm * 64;
  const int cbase = bn * 128 + wn * 64;
  if constexpr (OUT_MODE == 0) {
    if (cbase < 4096) {           // Q or K: row-major fp16, ld 2048
      _Float16* C = (_Float16*)Cv + (size_t)(cbase >> 11) * (4096ull * 2048);
#pragma unroll
      for (int mt = 0; mt < 4; ++mt)
#pragma unroll
        for (int nt = 0; nt < 4; ++nt) {
          int r0 = rbase + mt * 16 + l4 * 4;
          int cg = (cbase + nt * 16 + l15) & 2047;
#pragma unroll
          for (int r = 0; r < 4; ++r)
            C[(size_t)(r0 + r) * 2048 + cg] = (_Float16)acc[mt][nt][r];
        }
    } else {                      // V: per-batch transposed [b][d][s]
      _Float16* C = (_Float16*)Cv2;
#pragma unroll
      for (int mt = 0; mt < 4; ++mt)
#pragma unroll
        for (int nt = 0; nt < 4; ++nt) {
          int m0 = rbase + mt * 16 + l4 * 4;
          int d = cbase + nt * 16 + l15 - 4096;
          size_t base = (size_t)(m0 >> 11) * (2048ull * 2048) + (size_t)d * 2048 + (m0 & 2047);
          union { _Float16 h[4]; short4 s; } u;
#pragma unroll
          for (int r = 0; r < 4; ++r) u.h[r] = (_Float16)acc[mt][nt][r];
          *reinterpret_cast<short4*>(C + base) = u.s;
        }
    }
  } else {
    float* C = (float*)Cv + (size_t)blockIdx.z * 8388608ull;   // split-K partial
#pragma unroll
    for (int mt = 0; mt < 4; ++mt)
#pragma unroll
      for (int nt = 0; nt < 4; ++nt) {
        int r0 = rbase + mt * 16 + l4 * 4;
        int cg = cbase + nt * 16 + l15;
#pragma unroll
        for (int r = 0; r < 4; ++r)
          C[(size_t)(r0 + r) * 2048 + cg] = acc[mt][nt][r];
      }
  }
}

// ---- split-K reduce: out = p0 + p1 (float4) --------------------------------
__global__ void reduce_add(const float* __restrict__ p, float* __restrict__ out) {
  int i = blockIdx.x * blockDim.x + threadIdx.x;   // 2^21 quads
  float4 a = reinterpret_cast<const float4*>(p)[i];
  float4 b = reinterpret_cast<const float4*>(p + 8388608)[i];
  float4 o; o.x = a.x + b.x; o.y = a.y + b.y; o.z = a.z + b.z; o.w = a.w + b.w;
  reinterpret_cast<float4*>(out)[i] = o;
}

// ---- Flash attention (round-4 validated, unchanged) -------------------------
__global__ __launch_bounds__(256, 2)
void flash_attn(const _Float16* __restrict__ Q, const _Float16* __restrict__ Kg,
                const _Float16* __restrict__ Vt, _Float16* __restrict__ O) {
  __shared__ _Float16 Ks[64 * 128];   // [key][hd], 16-chunk xor swizzle
  __shared__ _Float16 Vs[128 * 64];   // [d][s],    8-chunk xor swizzle
  __shared__ _Float16 Ps[128 * 64];   // [q][key],  8-chunk xor swizzle
  const int tid = threadIdx.x, wave = tid >> 6, lane = tid & 63;
  const int l15 = lane & 15, l4 = lane >> 4;
  const int bh = blockIdx.y, b = bh >> 4, h = bh & 15;
  const int q0 = blockIdx.x * 128;

  const _Float16* Qp = Q + ((size_t)(b * 2048 + q0 + wave * 32)) * 2048 + h * 128;
  const _Float16* Kp = Kg + (size_t)b * 2048 * 2048 + h * 128;
  const _Float16* Vp = Vt + (size_t)b * 2048 * 2048 + (size_t)(h * 128) * 2048;

  half8 qf[2][4];
#pragma unroll
  for (int mt = 0; mt < 2; ++mt)
#pragma unroll
    for (int ks = 0; ks < 4; ++ks)
      qf[mt][ks] = *reinterpret_cast<const half8*>(
          Qp + (size_t)(mt * 16 + l15) * 2048 + ks * 32 + l4 * 8);

  floatx4 oacc[2][8] = {};
  float lsum[2][4] = {};

  for (int k0 = 0; k0 < 2048; k0 += 64) {
    __syncthreads();
#pragma unroll
    for (int i = 0; i < 4; ++i) {                 // K: 64 rows x 16 chunks
      int c = i * 256 + tid;
      int row = c >> 4, cc = c & 15;
      int g = cc ^ (row & 15);
      async16(Kp + (size_t)(k0 + row) * 2048 + g * 8, &Ks[c * 8]);
    }
#pragma unroll
    for (int i = 0; i < 4; ++i) {                 // V: 128 rows x 8 chunks
      int c = i * 256 + tid;
      int row = c >> 3, cc = c & 7;
      int g = cc ^ (row & 7);
      async16(Vp + (size_t)row * 2048 + k0 + g * 8, &Vs[c * 8]);
    }
    __syncthreads();

    floatx4 sacc[2][4] = {};
#pragma unroll
    for (int ks = 0; ks < 4; ++ks) {
      half8 bf[4];
#pragma unroll
      for (int nt = 0; nt < 4; ++nt) {
        int row = nt * 16 + l15;
        int ch = (ks * 4 + l4) ^ l15;
        bf[nt] = *reinterpret_cast<const half8*>(&Ks[row * 128 + ch * 8]);
      }
#pragma unroll
      for (int mt = 0; mt < 2; ++mt)
#pragma unroll
        for (int nt = 0; nt < 4; ++nt)
          sacc[mt][nt] = __builtin_amdgcn_mfma_f32_16x16x32_f16(qf[mt][ks], bf[nt], sacc[mt][nt], 0, 0, 0);
    }

#pragma unroll
    for (int mt = 0; mt < 2; ++mt)
#pragma unroll
      for (int nt = 0; nt < 4; ++nt)
#pragma unroll
        for (int r = 0; r < 4; ++r) {
          float p = exp2f(sacc[mt][nt][r]);
          lsum[mt][r] += p;
          int rl = l4 * 4 + r;
          int ch = (nt * 2 + (l15 >> 3)) ^ (rl & 7);
          Ps[(wave * 32 + mt * 16 + rl) * 64 + ch * 8 + (l15 & 7)] = (_Float16)p;
        }

    __builtin_amdgcn_s_waitcnt(0xC07F);  // lgkmcnt(0)

#pragma unroll
    for (int ks2 = 0; ks2 < 2; ++ks2) {
      half8 pf[2];
#pragma unroll
      for (int mt = 0; mt < 2; ++mt)
        pf[mt] = *reinterpret_cast<const half8*>(
            &Ps[(wave * 32 + mt * 16 + l15) * 64 + (((ks2 * 4 + l4) ^ (l15 & 7)) * 8)]);
#pragma unroll
      for (int nt2 = 0; nt2 < 8; ++nt2) {
        int row = nt2 * 16 + l15;
        int ch = (ks2 * 4 + l4) ^ (row & 7);
        half8 vf = *reinterpret_cast<const half8*>(&Vs[row * 64 + ch * 8]);
#pragma unroll
        for (int mt = 0; mt < 2; ++mt)
          oacc[mt][nt2] = __builtin_amdgcn_mfma_f32_16x16x32_f16(pf[mt], vf, oacc[mt][nt2], 0, 0, 0);
      }
    }
  }

#pragma unroll
  for (int mt = 0; mt < 2; ++mt)
#pragma unroll
    for (int r = 0; r < 4; ++r) {
#pragma unroll
      for (int off = 1; off < 16; off <<= 1) lsum[mt][r] += __shfl_xor(lsum[mt][r], off);
    }

  _Float16* Op = O + ((size_t)(b * 2048 + q0 + wave * 32)) * 2048 + h * 128;
#pragma unroll
  for (int mt = 0; mt < 2; ++mt)
#pragma unroll
    for (int r = 0; r < 4; ++r) {
      float inv = 1.0f / lsum[mt][r];
#pragma unroll
      for (int nt2 = 0; nt2 < 8; ++nt2) {
        int row = mt * 16 + l4 * 4 + r;
        int col = nt2 * 16 + l15;
        Op[(size_t)row * 2048 + col] = (_Float16)(oacc[mt][nt2][r] * inv);
      }
    }
}

// ---------------------------------------------------------------------------
extern "C" void kernel_launch(void* const* d_in, const int* in_sizes, int n_in,
                              void* d_out, int out_size, void* d_ws, size_t ws_size,
                              hipStream_t stream) {
  const float* x = (const float*)d_in[0];
  const float* wq = (const float*)d_in[1];
  const float* wk = (const float*)d_in[2];
  const float* wv = (const float*)d_in[3];
  const float* wo = (const float*)d_in[4];
  float* out = (float*)d_out;

  const size_t XN = (size_t)4096 * 2048;
  const size_t WN = (size_t)2048 * 2048;
  _Float16* xh = (_Float16*)d_ws;
  _Float16* qh = xh + XN;          // Q then K contiguous (row-major, ld 2048)
  _Float16* vth = xh + 3 * XN;     // per-batch transposed V
  _Float16* oh = xh + 4 * XN;
  _Float16* wqh = xh + 5 * XN;     // wq,wk,wv,wo contiguous
  float* pparts = (float*)d_ws;    // split-K partials over dead xh..vth (67 MB)

  const float SM_SCALE = 0.08838834764831845f * 1.4426950408889634f;

  cvt_all<<<dim3(24576), 256, 0, stream>>>(x, wq, wk, wv, wo, xh, wqh, SM_SCALE);
  gemm_nt<0><<<dim3(48, 32), 256, 0, stream>>>(xh, wqh, qh, vth, 2048);
  flash_attn<<<dim3(16, 32), 256, 0, stream>>>(qh, qh + XN, vth, oh);
  gemm_nt<2><<<dim3(16, 32, 2), 256, 0, stream>>>(oh, wqh + 3 * WN, pparts, nullptr, 1024);
  reduce_add<<<dim3(8192), 256, 0, stream>>>(pparts, out);
}

// Round 7
// 396.778 us; speedup vs baseline: 1.0691x; 1.0691x over previous
//
#include <hip/hip_runtime.h>

// ---------------------------------------------------------------------------
// Fused MHA block on MI355X (gfx950). fp16 MFMA 16x16x32, fp32 accum.
// Round-7:
//  * split-K REVERTED (r6: +18 us — reduce kernel cost ~20 us, GEMM gain ~0;
//    wo-GEMM is barrier-economics bound, not occupancy bound).
//  * flash: S computed TRANSPOSED (mfma(K_frag, Q_frag) -> col=q, row=s).
//    Each lane then holds 4 consecutive s for one q -> Ps written as packed
//    ds_write_b64 (8/iter instead of 32 scalar b16). Flash is LDS-pipe bound
//    (~36 b128 reads + 32 b16 writes vs 64 MFMA per wave-iter); this cuts the
//    write-side issue cost ~60%. lsum becomes per-lane scalar per q-tile
//    (2 shuffles to reduce, dynamic shfl in epilogue).
// ---------------------------------------------------------------------------

typedef _Float16 half8 __attribute__((ext_vector_type(8)));
typedef _Float16 half4 __attribute__((ext_vector_type(4)));
typedef float floatx4 __attribute__((ext_vector_type(4)));

__device__ __forceinline__ void async16(const void* g, void* l) {
  __builtin_amdgcn_global_load_lds((__attribute__((address_space(1))) void*)(g),
                                   (__attribute__((address_space(3))) void*)(l),
                                   16, 0, 0);
}

// ---- fp32 -> fp16 convert: x (2^21 quads) then 4 weights (2^20 each) -------
__global__ void cvt_all(const float* __restrict__ x, const float* __restrict__ w0,
                        const float* __restrict__ w1, const float* __restrict__ w2,
                        const float* __restrict__ w3, _Float16* __restrict__ xh,
                        _Float16* __restrict__ wh, float scale0) {
  int i = blockIdx.x * blockDim.x + threadIdx.x;
  const int XQ = 1 << 21;
  float sc = 1.0f;
  const float* src;
  _Float16* dst;
  int j;
  if (i < XQ) { src = x; dst = xh; j = i; }
  else {
    int t = i - XQ;
    int m = t >> 20;
    src = (m == 0) ? w0 : (m == 1) ? w1 : (m == 2) ? w2 : w3;
    if (m == 0) sc = scale0;
    dst = wh; j = t;
  }
  int js = (i < XQ) ? j : (j & ((1 << 20) - 1));
  float4 v = reinterpret_cast<const float4*>(src)[js];
  union { _Float16 h[4]; short4 s; } u;
  u.h[0] = (_Float16)(v.x * sc); u.h[1] = (_Float16)(v.y * sc);
  u.h[2] = (_Float16)(v.z * sc); u.h[3] = (_Float16)(v.w * sc);
  reinterpret_cast<short4*>(dst)[j] = u.s;
}

// ---- NT GEMM (16x16x32): C[m][n] = sum_k A[m][k]*Bw[n][k], 128x128 tile ----
// OUT_MODE 0: fused QKV epilogue. OUT_MODE 2: fp32 row-major to d_out.
template <int OUT_MODE>
__global__ __launch_bounds__(256)
void gemm_nt(const _Float16* __restrict__ A, const _Float16* __restrict__ Bw,
             void* __restrict__ Cv, void* __restrict__ Cv2) {
  __shared__ _Float16 As[128 * 64];
  __shared__ _Float16 Bs[128 * 64];
  const int tid = threadIdx.x;
  const int wave = tid >> 6, lane = tid & 63;
  const int wm = wave >> 1, wn = wave & 1;
  const int l15 = lane & 15, l4 = lane >> 4;
  const int bm = blockIdx.y, bn = blockIdx.x;

  floatx4 acc[4][4] = {};

  for (int k0 = 0; k0 < 2048; k0 += 64) {
    __syncthreads();
#pragma unroll
    for (int i = 0; i < 4; ++i) {
      int c = i * 256 + tid;
      int row = c >> 3, cc = c & 7;
      int g = cc ^ (row & 7);                       // xor-swizzle global chunk
      async16(A + (size_t)(bm * 128 + row) * 2048 + k0 + g * 8, &As[c * 8]);
      async16(Bw + (size_t)(bn * 128 + row) * 2048 + k0 + g * 8, &Bs[c * 8]);
    }
    __syncthreads();
#pragma unroll
    for (int ks = 0; ks < 2; ++ks) {
      half8 af[4], bf[4];
      int ch = (ks * 4 + l4) ^ (l15 & 7);           // matching read swizzle
#pragma unroll
      for (int t = 0; t < 4; ++t) {
        af[t] = *reinterpret_cast<const half8*>(&As[(wm * 64 + t * 16 + l15) * 64 + ch * 8]);
        bf[t] = *reinterpret_cast<const half8*>(&Bs[(wn * 64 + t * 16 + l15) * 64 + ch * 8]);
      }
#pragma unroll
      for (int mt = 0; mt < 4; ++mt)
#pragma unroll
        for (int nt = 0; nt < 4; ++nt)
          acc[mt][nt] = __builtin_amdgcn_mfma_f32_16x16x32_f16(af[mt], bf[nt], acc[mt][nt], 0, 0, 0);
    }
  }

  const int rbase = bm * 128 + wm * 64;
  const int cbase = bn * 128 + wn * 64;
  if constexpr (OUT_MODE == 0) {
    if (cbase < 4096) {           // Q or K: row-major fp16, ld 2048
      _Float16* C = (_Float16*)Cv + (size_t)(cbase >> 11) * (4096ull * 2048);
#pragma unroll
      for (int mt = 0; mt < 4; ++mt)
#pragma unroll
        for (int nt = 0; nt < 4; ++nt) {
          int r0 = rbase + mt * 16 + l4 * 4;
          int cg = (cbase + nt * 16 + l15) & 2047;
#pragma unroll
          for (int r = 0; r < 4; ++r)
            C[(size_t)(r0 + r) * 2048 + cg] = (_Float16)acc[mt][nt][r];
        }
    } else {                      // V: per-batch transposed [b][d][s]
      _Float16* C = (_Float16*)Cv2;
#pragma unroll
      for (int mt = 0; mt < 4; ++mt)
#pragma unroll
        for (int nt = 0; nt < 4; ++nt) {
          int m0 = rbase + mt * 16 + l4 * 4;
          int d = cbase + nt * 16 + l15 - 4096;
          size_t base = (size_t)(m0 >> 11) * (2048ull * 2048) + (size_t)d * 2048 + (m0 & 2047);
          union { _Float16 h[4]; short4 s; } u;
#pragma unroll
          for (int r = 0; r < 4; ++r) u.h[r] = (_Float16)acc[mt][nt][r];
          *reinterpret_cast<short4*>(C + base) = u.s;
        }
    }
  } else {
    float* C = (float*)Cv;
#pragma unroll
    for (int mt = 0; mt < 4; ++mt)
#pragma unroll
      for (int nt = 0; nt < 4; ++nt) {
        int r0 = rbase + mt * 16 + l4 * 4;
        int cg = cbase + nt * 16 + l15;
#pragma unroll
        for (int r = 0; r < 4; ++r)
          C[(size_t)(r0 + r) * 2048 + cg] = acc[mt][nt][r];
      }
  }
}

// ---- Flash attention --------------------------------------------------------
// grid = (16 q-tiles of 128, 32 b*h); block = 256 (4 waves x 32 q rows).
// Fixed-max softmax: p = 2^(s'), s' = q.k with 1/sqrt(128)*log2(e) pre-folded.
// S computed TRANSPOSED: sacc[st][qt] holds col=q(lane&15), row=s(quad*4+r),
// so each lane packs 4 consecutive s into one ds_write_b64 of Ps[q][s].
__global__ __launch_bounds__(256, 2)
void flash_attn(const _Float16* __restrict__ Q, const _Float16* __restrict__ Kg,
                const _Float16* __restrict__ Vt, _Float16* __restrict__ O) {
  __shared__ _Float16 Ks[64 * 128];   // [key][hd], 16-chunk xor swizzle
  __shared__ _Float16 Vs[128 * 64];   // [d][s],    8-chunk xor swizzle
  __shared__ _Float16 Ps[128 * 64];   // [q][key],  8-chunk xor swizzle
  const int tid = threadIdx.x, wave = tid >> 6, lane = tid & 63;
  const int l15 = lane & 15, l4 = lane >> 4;
  const int bh = blockIdx.y, b = bh >> 4, h = bh & 15;
  const int q0 = blockIdx.x * 128;

  const _Float16* Qp = Q + ((size_t)(b * 2048 + q0 + wave * 32)) * 2048 + h * 128;
  const _Float16* Kp = Kg + (size_t)b * 2048 * 2048 + h * 128;
  const _Float16* Vp = Vt + (size_t)b * 2048 * 2048 + (size_t)(h * 128) * 2048;

  half8 qf[2][4];
#pragma unroll
  for (int qt = 0; qt < 2; ++qt)
#pragma unroll
    for (int ks = 0; ks < 4; ++ks)
      qf[qt][ks] = *reinterpret_cast<const half8*>(
          Qp + (size_t)(qt * 16 + l15) * 2048 + ks * 32 + l4 * 8);

  floatx4 oacc[2][8] = {};
  float lsumq[2] = {0.f, 0.f};        // per-lane: sum over its s for q = lane&15

  for (int k0 = 0; k0 < 2048; k0 += 64) {
    __syncthreads();
#pragma unroll
    for (int i = 0; i < 4; ++i) {                 // K: 64 rows x 16 chunks
      int c = i * 256 + tid;
      int row = c >> 4, cc = c & 15;
      int g = cc ^ (row & 15);
      async16(Kp + (size_t)(k0 + row) * 2048 + g * 8, &Ks[c * 8]);
    }
#pragma unroll
    for (int i = 0; i < 4; ++i) {                 // V: 128 rows x 8 chunks
      int c = i * 256 + tid;
      int row = c >> 3, cc = c & 7;
      int g = cc ^ (row & 7);
      async16(Vp + (size_t)row * 2048 + k0 + g * 8, &Vs[c * 8]);
    }
    __syncthreads();

    // ---- S^T = K Q^T : sacc[st][qt], col=q, row=s ----
    floatx4 sacc[4][2] = {};
#pragma unroll
    for (int ks = 0; ks < 4; ++ks) {
      half8 kf[4];
#pragma unroll
      for (int st = 0; st < 4; ++st) {
        int row = st * 16 + l15;
        int ch = (ks * 4 + l4) ^ l15;             // row & 15 == l15
        kf[st] = *reinterpret_cast<const half8*>(&Ks[row * 128 + ch * 8]);
      }
#pragma unroll
      for (int st = 0; st < 4; ++st)
#pragma unroll
        for (int qt = 0; qt < 2; ++qt)
          sacc[st][qt] = __builtin_amdgcn_mfma_f32_16x16x32_f16(kf[st], qf[qt][ks], sacc[st][qt], 0, 0, 0);
    }

    // ---- p = 2^s; packed b64 Ps write (4 consecutive s per lane) ----
#pragma unroll
    for (int qt = 0; qt < 2; ++qt)
#pragma unroll
      for (int st = 0; st < 4; ++st) {
        float p0 = exp2f(sacc[st][qt][0]);
        float p1 = exp2f(sacc[st][qt][1]);
        float p2 = exp2f(sacc[st][qt][2]);
        float p3 = exp2f(sacc[st][qt][3]);
        lsumq[qt] += (p0 + p1) + (p2 + p3);
        half4 pv;
        pv[0] = (_Float16)p0; pv[1] = (_Float16)p1;
        pv[2] = (_Float16)p2; pv[3] = (_Float16)p3;
        // s = st*16 + l4*4 + r -> pre-swizzle chunk (s/8) = st*2 + (l4>>1),
        // within-chunk 8B half = l4&1. Swizzle chunk by row&7 (= l15&7).
        int ch = (st * 2 + (l4 >> 1)) ^ (l15 & 7);
        *reinterpret_cast<half4*>(
            &Ps[(wave * 32 + qt * 16 + l15) * 64 + ch * 8 + (l4 & 1) * 4]) = pv;
      }

    __builtin_amdgcn_s_waitcnt(0xC07F);  // lgkmcnt(0): own-wave ds_write->ds_read

    // ---- O += P V  (V stored (d,s): NT GEMM) ----
#pragma unroll
    for (int ks2 = 0; ks2 < 2; ++ks2) {
      half8 pf[2];
#pragma unroll
      for (int mt = 0; mt < 2; ++mt)
        pf[mt] = *reinterpret_cast<const half8*>(
            &Ps[(wave * 32 + mt * 16 + l15) * 64 + (((ks2 * 4 + l4) ^ (l15 & 7)) * 8)]);
#pragma unroll
      for (int nt2 = 0; nt2 < 8; ++nt2) {
        int row = nt2 * 16 + l15;
        int ch = (ks2 * 4 + l4) ^ (row & 7);
        half8 vf = *reinterpret_cast<const half8*>(&Vs[row * 64 + ch * 8]);
#pragma unroll
        for (int mt = 0; mt < 2; ++mt)
          oacc[mt][nt2] = __builtin_amdgcn_mfma_f32_16x16x32_f16(pf[mt], vf, oacc[mt][nt2], 0, 0, 0);
      }
    }
  }

  // lsumq holds the partial row-sum for q = lane&15, spread over the 4 quads.
#pragma unroll
  for (int qt = 0; qt < 2; ++qt) {
    lsumq[qt] += __shfl_xor(lsumq[qt], 16);
    lsumq[qt] += __shfl_xor(lsumq[qt], 32);
  }

  _Float16* Op = O + ((size_t)(b * 2048 + q0 + wave * 32)) * 2048 + h * 128;
#pragma unroll
  for (int mt = 0; mt < 2; ++mt)
#pragma unroll
    for (int r = 0; r < 4; ++r) {
      // O row q = mt*16 + l4*4 + r; its lsum lives at lane (l4*4 + r).
      float inv = 1.0f / __shfl(lsumq[mt], l4 * 4 + r);
#pragma unroll
      for (int nt2 = 0; nt2 < 8; ++nt2) {
        int row = mt * 16 + l4 * 4 + r;
        int col = nt2 * 16 + l15;
        Op[(size_t)row * 2048 + col] = (_Float16)(oacc[mt][nt2][r] * inv);
      }
    }
}

// ---------------------------------------------------------------------------
extern "C" void kernel_launch(void* const* d_in, const int* in_sizes, int n_in,
                              void* d_out, int out_size, void* d_ws, size_t ws_size,
                              hipStream_t stream) {
  const float* x = (const float*)d_in[0];
  const float* wq = (const float*)d_in[1];
  const float* wk = (const float*)d_in[2];
  const float* wv = (const float*)d_in[3];
  const float* wo = (const float*)d_in[4];
  float* out = (float*)d_out;

  const size_t XN = (size_t)4096 * 2048;
  const size_t WN = (size_t)2048 * 2048;
  _Float16* xh = (_Float16*)d_ws;
  _Float16* qh = xh + XN;          // Q then K contiguous (row-major, ld 2048)
  _Float16* vth = xh + 3 * XN;     // per-batch transposed V
  _Float16* oh = xh + 4 * XN;
  _Float16* wqh = xh + 5 * XN;     // wq,wk,wv,wo contiguous

  const float SM_SCALE = 0.08838834764831845f * 1.4426950408889634f;

  cvt_all<<<dim3(24576), 256, 0, stream>>>(x, wq, wk, wv, wo, xh, wqh, SM_SCALE);
  gemm_nt<0><<<dim3(48, 32), 256, 0, stream>>>(xh, wqh, qh, vth);
  flash_attn<<<dim3(16, 32), 256, 0, stream>>>(qh, qh + XN, vth, oh);
  gemm_nt<2><<<dim3(16, 32), 256, 0, stream>>>(oh, wqh + 3 * WN, out, nullptr);
}